// Round 1
// baseline (21328.400 us; speedup 1.0000x reference)
//
#include <hip/hip_runtime.h>
#include <hip/hip_cooperative_groups.h>

namespace cg = cooperative_groups;

#define VOCABN 32000
#define EN 256
#define HN 512
#define BN 64
#define TN 512
#define KTOT 768   // E + H fused contraction

constexpr int NBLK = 256;   // LSTM blocks; each owns 2 h-columns
constexpr int BLKT = 512;   // 8 waves: 4 gates x 2 K-halves

// ---------------- Kernel A: weT[t][e][b] = emb[x[b][t]][e] (transposed) ---
__global__ __launch_bounds__(256) void embed_transpose_kernel(
    float* __restrict__ weT, const int* __restrict__ x,
    const float* __restrict__ emb)
{
  __shared__ float tile[64][65];
  const int t    = blockIdx.x;
  const int tid  = threadIdx.x;
  const int lane = tid & 63;
  const int grp  = tid >> 6;   // 0..3
  for (int ec = 0; ec < EN; ec += 64) {
    // read phase: lanes sweep e (coalesced 256B per row)
    for (int i = 0; i < 16; i++) {
      int b = grp * 16 + i;
      int row = x[b * TN + t];
      tile[lane][b] = emb[(size_t)row * EN + ec + lane];
    }
    __syncthreads();
    // write phase: lanes sweep b (coalesced)
    for (int i = 0; i < 16; i++) {
      int e = grp * 16 + i;
      weT[((size_t)t * EN + ec + e) * BN + lane] = tile[e][lane];
    }
    __syncthreads();
  }
}

// ---------------- Kernel B: persistent cooperative LSTM -------------------
// Block k owns h-columns {2k, 2k+1}. Weights for its 8 gate rows live in LDS
// for the whole scan. h double-buffered in ws, transposed [H][B] for
// coalesced lane=b loads. One grid.sync() per timestep.
__global__ __launch_bounds__(512) void lstm_kernel(
    const float* __restrict__ weT, float* __restrict__ hbuf,
    float* __restrict__ part,
    const int* __restrict__ length,
    const float* __restrict__ Wih, const float* __restrict__ Whh,
    const float* __restrict__ bih, const float* __restrict__ bhh,
    const float* __restrict__ Wcls, const float* __restrict__ bcls,
    float* __restrict__ out)
{
  cg::grid_group grid = cg::this_grid();
  __shared__ float Wl[8][KTOT];       // [g*2+jj][k]   24KB, resident all scan
  __shared__ float gl[2][4][2][64];   // [khalf][gate][jj][b] partial gates
  __shared__ float bl[8];

  const int tid = threadIdx.x;
  const int b   = tid & 63;
  const int g   = (tid >> 6) & 3;     // gate 0..3
  const int s   = tid >> 8;           // K-half 0/1
  const int j0  = blockIdx.x * 2;

  // stage weight slice: rows {g*H + j0 + jj}, k<E from W_ih else W_hh
  for (int idx = tid; idx < 8 * KTOT; idx += BLKT) {
    int r = idx / KTOT, k = idx - r * KTOT;
    int wrow = (r >> 1) * HN + j0 + (r & 1);
    Wl[r][k] = (k < EN) ? Wih[(size_t)wrow * EN + k]
                        : Whh[(size_t)wrow * HN + (k - EN)];
  }
  if (tid < 8) {
    int wrow = (tid >> 1) * HN + j0 + (tid & 1);
    bl[tid] = bih[wrow] + bhh[wrow];
  }

  // per-(b,jj) recurrent state lives in threads tid<128
  const int jj = tid >> 6;            // valid when tid<128
  float c = 0.f, fmaxv = -INFINITY;
  int len = 0;
  if (tid < 128) {
    len = length[b];
    hbuf[(size_t)(j0 + jj) * BN + b] = 0.f;   // zero h buffer 0
  }
  grid.sync();

  int cur = 0;
  for (int t = 0; t < TN; t++) {
    const float* xp = weT + (size_t)t * EN * BN + b;
    const float* hp = hbuf + (size_t)cur * HN * BN + b;
    const float* w0 = Wl[g * 2];
    const float* w1 = Wl[g * 2 + 1];
    float a0 = 0.f, a1 = 0.f;
    if (s == 0) {   // k in [0, 384): all E + first 128 of H
      #pragma unroll 8
      for (int k = 0; k < EN; k++) {
        float v = xp[(size_t)k * BN];
        a0 += v * w0[k]; a1 += v * w1[k];
      }
      #pragma unroll 8
      for (int k = 0; k < 128; k++) {
        float v = hp[(size_t)k * BN];
        a0 += v * w0[EN + k]; a1 += v * w1[EN + k];
      }
    } else {        // k in [384, 768): h[128..512)
      #pragma unroll 8
      for (int k = 128; k < HN; k++) {
        float v = hp[(size_t)k * BN];
        a0 += v * w0[EN + k]; a1 += v * w1[EN + k];
      }
    }
    gl[s][g][0][b] = a0;
    gl[s][g][1][b] = a1;
    __syncthreads();

    if (tid < 128) {
      float gi = gl[0][0][jj][b] + gl[1][0][jj][b] + bl[0 + jj];
      float gf = gl[0][1][jj][b] + gl[1][1][jj][b] + bl[2 + jj];
      float gg = gl[0][2][jj][b] + gl[1][2][jj][b] + bl[4 + jj];
      float go = gl[0][3][jj][b] + gl[1][3][jj][b] + bl[6 + jj];
      float si = 1.f / (1.f + __expf(-gi));
      float sf = 1.f / (1.f + __expf(-gf));
      float so = 1.f / (1.f + __expf(-go));
      float tg = 2.f / (1.f + __expf(-2.f * gg)) - 1.f;
      c = sf * c + si * tg;
      float tc = 2.f / (1.f + __expf(-2.f * c)) - 1.f;
      float h = so * tc;
      hbuf[(size_t)(cur ^ 1) * HN * BN + (size_t)(j0 + jj) * BN + b] = h;
      if (t < len) fmaxv = fmaxf(fmaxv, h);
    }
    grid.sync();
    cur ^= 1;
  }

  // classifier partials: p[cls][b] = sum_jj fmax(b,j0+jj) * Wcls[cls][j0+jj]
  if (tid < 128) {
    gl[0][0][jj][b] = fmaxv * Wcls[0 * HN + j0 + jj];
    gl[0][1][jj][b] = fmaxv * Wcls[1 * HN + j0 + jj];
  }
  __syncthreads();
  if (tid < 128) {
    int cls = jj;
    part[(size_t)blockIdx.x * 128 + cls * 64 + b] =
        gl[0][cls][0][b] + gl[0][cls][1][b];
  }
  grid.sync();
  if (blockIdx.x == 0 && tid < 128) {
    int cls = tid >> 6;
    float sum = bcls[cls];
    for (int k = 0; k < NBLK; k++)
      sum += part[(size_t)k * 128 + cls * 64 + b];
    out[b * 2 + cls] = sum;
  }
}

extern "C" void kernel_launch(void* const* d_in, const int* in_sizes, int n_in,
                              void* d_out, int out_size, void* d_ws, size_t ws_size,
                              hipStream_t stream) {
  const int*   x    = (const int*)d_in[0];
  const int*   len  = (const int*)d_in[1];
  const float* emb  = (const float*)d_in[2];
  const float* Wih  = (const float*)d_in[3];
  const float* Whh  = (const float*)d_in[4];
  const float* bih  = (const float*)d_in[5];
  const float* bhh  = (const float*)d_in[6];
  const float* Wcls = (const float*)d_in[7];
  const float* bcls = (const float*)d_in[8];
  float* out = (float*)d_out;

  float* weT  = (float*)d_ws;                       // T*E*B   = 8,388,608 f32
  float* hbuf = weT + (size_t)TN * EN * BN;         // 2*H*B   = 65,536 f32
  float* part = hbuf + (size_t)2 * HN * BN;         // NBLK*128= 32,768 f32

  embed_transpose_kernel<<<dim3(TN), dim3(256), 0, stream>>>(weT, x, emb);

  void* args[] = { (void*)&weT, (void*)&hbuf, (void*)&part, (void*)&len,
                   (void*)&Wih, (void*)&Whh, (void*)&bih, (void*)&bhh,
                   (void*)&Wcls, (void*)&bcls, (void*)&out };
  hipLaunchCooperativeKernel((void*)lstm_kernel, dim3(NBLK), dim3(BLKT),
                             args, 0, stream);
}

// Round 2
// 11717.344 us; speedup vs baseline: 1.8202x; 1.8202x over previous
//
#include <hip/hip_runtime.h>
#include <hip/hip_bf16.h>

#define EN 256
#define HN 512
#define BN 64
#define TN 512
#define NBLK 64
#define KCAT 1280   // 256 Wih_hi | 512 Whh_hi | 512 Whh_lo

typedef __attribute__((ext_vector_type(8))) short short8;
typedef __attribute__((ext_vector_type(4))) short short4v;
typedef __attribute__((ext_vector_type(4))) float f32x4;

__device__ inline short bf_of(float f) {
  __hip_bfloat16 h = __float2bfloat16(f);
  return *reinterpret_cast<short*>(&h);
}
__device__ inline float f_of_bf(short s) {
  __hip_bfloat16 h = *reinterpret_cast<__hip_bfloat16*>(&s);
  return __bfloat162float(h);
}

// ---------- K0: zero h-buffer 0 and the barrier counter ----------
__global__ __launch_bounds__(256) void zero_kernel(unsigned* hbuf_u32, int* bar) {
  int idx = blockIdx.x * 256 + threadIdx.x;
  if (idx < (BN * HN * 2) / 4) hbuf_u32[idx] = 0;   // zero 64KB (buffer 0)
  if (idx == 0) *bar = 0;
}

// ---------- K1: weB[t*64+b][k] = bf16(emb[x[b][t]][k]) ----------
__global__ __launch_bounds__(256) void gather_kernel(
    short* __restrict__ weB, const int* __restrict__ x,
    const float* __restrict__ emb) {
  const int t = blockIdx.x;
  const int tid = threadIdx.x;
  const int b = tid >> 2, q = tid & 3;
  const int row = x[b * TN + t];
  const float4* src = (const float4*)(emb + (size_t)row * EN + q * 64);
  short* dst = weB + ((size_t)(t * 64 + b)) * EN + q * 64;
#pragma unroll
  for (int i = 0; i < 16; i++) {
    float4 v = src[i];
    short4v o = { bf_of(v.x), bf_of(v.y), bf_of(v.z), bf_of(v.w) };
    *(short4v*)(dst + i * 4) = o;
  }
}

// ---------- K2: Wall[grow][kc]: kc<256 Wih_hi | <768 Whh_hi | else Whh_lo --
__global__ __launch_bounds__(256) void prep_w_kernel(
    short* __restrict__ Wall, const float* __restrict__ Wih,
    const float* __restrict__ Whh) {
  int idx = blockIdx.x * 256 + threadIdx.x;   // 2048*1280 total
  int grow = idx / KCAT, kc = idx - grow * KCAT;
  float v;
  if (kc < 256) {
    v = Wih[(size_t)grow * EN + kc];
  } else if (kc < 768) {
    v = Whh[(size_t)grow * HN + (kc - 256)];
  } else {
    float f = Whh[(size_t)grow * HN + (kc - 768)];
    v = f - f_of_bf(bf_of(f));                // residual (lo) term
  }
  Wall[idx] = bf_of(v);
}

// ---------- custom grid barrier (blocks are co-resident: coop launch) -----
__device__ inline void gridbar(int* bar, int target) {
  __threadfence();
  __syncthreads();
  if (threadIdx.x == 0) {
    __hip_atomic_fetch_add(bar, 1, __ATOMIC_ACQ_REL, __HIP_MEMORY_SCOPE_AGENT);
    while (__hip_atomic_load(bar, __ATOMIC_ACQUIRE, __HIP_MEMORY_SCOPE_AGENT) < target) {
      __builtin_amdgcn_s_sleep(1);
    }
  }
  __syncthreads();
}

// ---------- scan: 64 blocks x 512 thr, block owns h-cols [8*blk, 8*blk+8) --
__global__ __launch_bounds__(512, 2) void scan_kernel(
    const short* __restrict__ weB, const short* __restrict__ Wall,
    short* __restrict__ hbuf, const int* __restrict__ length,
    const float* __restrict__ bih, const float* __restrict__ bhh,
    const float* __restrict__ Wcls, const float* __restrict__ bcls,
    float* __restrict__ part, int* bar, float* __restrict__ out) {
  __shared__ float gl[32][64];   // local gate rows r = type*8+jj, col b
  const int tid = threadIdx.x;
  const int l = tid & 63, w = tid >> 6;
  const int j0 = blockIdx.x * 8;

  // --- MFMA role: wave w -> C tile rows [rhalf, rhalf+16), cols [btile,+16)
  const int btile = (w & 3) * 16;
  const int rhalf = (w >> 2) * 16;

  short8 aH[24], aL[16];
  {
    int r = rhalf + (l & 15);
    int grow = (r >> 3) * HN + j0 + (r & 7);
    const short* wp = Wall + (size_t)grow * KCAT + 8 * (l >> 4);
#pragma unroll
    for (int kk = 0; kk < 24; kk++) aH[kk] = *(const short8*)(wp + kk * 32);
#pragma unroll
    for (int kk = 0; kk < 16; kk++) aL[kk] = *(const short8*)(wp + 768 + kk * 32);
  }

  // --- elementwise role: thread -> (jj = w, b = l)
  const int jj = w, b = l;
  float bias[4];
#pragma unroll
  for (int ty = 0; ty < 4; ty++) {
    int grow = ty * HN + j0 + jj;
    bias[ty] = bih[grow] + bhh[grow];
  }
  const int len = length[b];
  float c = 0.f, fmx = -INFINITY;
  int target = NBLK;

  for (int t = 0; t < TN; t++) {
    const short* xrow = weB + ((size_t)(t * 64 + btile + (l & 15))) * EN + 8 * (l >> 4);
    const short* hrow = hbuf + (size_t)(t & 1) * (BN * HN)
                             + (size_t)(btile + (l & 15)) * HN + 8 * (l >> 4);
    f32x4 accH = {0.f, 0.f, 0.f, 0.f}, accL = {0.f, 0.f, 0.f, 0.f};
#pragma unroll
    for (int kk = 0; kk < 8; kk++) {   // x-side: K = 0..255
      short8 bf = *(const short8*)(xrow + kk * 32);
      accH = __builtin_amdgcn_mfma_f32_16x16x32_bf16(aH[kk], bf, accH, 0, 0, 0);
    }
#pragma unroll
    for (int kk = 0; kk < 16; kk++) {  // h-side: K = 256..767, hi + lo chains
      short8 bf = *(const short8*)(hrow + kk * 32);
      accH = __builtin_amdgcn_mfma_f32_16x16x32_bf16(aH[8 + kk], bf, accH, 0, 0, 0);
      accL = __builtin_amdgcn_mfma_f32_16x16x32_bf16(aL[kk], bf, accL, 0, 0, 0);
    }
#pragma unroll
    for (int q = 0; q < 4; q++) {      // C/D: col = lane&15, row = (lane>>4)*4+q
      int r = rhalf + (l >> 4) * 4 + q;
      gl[r][btile + (l & 15)] = accH[q] + accL[q];
    }
    __syncthreads();
    {
      float gi = gl[0 + jj][b] + bias[0];
      float gf = gl[8 + jj][b] + bias[1];
      float gg = gl[16 + jj][b] + bias[2];
      float go = gl[24 + jj][b] + bias[3];
      float si = 1.f / (1.f + __expf(-gi));
      float sf = 1.f / (1.f + __expf(-gf));
      float so = 1.f / (1.f + __expf(-go));
      float tg = 2.f / (1.f + __expf(-2.f * gg)) - 1.f;
      c = sf * c + si * tg;
      float tc = 2.f / (1.f + __expf(-2.f * c)) - 1.f;
      float h = so * tc;
      hbuf[(size_t)((t + 1) & 1) * (BN * HN) + (size_t)b * HN + j0 + jj] = bf_of(h);
      if (t < len) fmx = fmaxf(fmx, h);
    }
    gridbar(bar, target);
    target += NBLK;
  }

  // --- classifier partials: pc[cls][jj][b] in gl, reduce over jj ---
  gl[jj][b]     = fmx * Wcls[j0 + jj];
  gl[8 + jj][b] = fmx * Wcls[HN + j0 + jj];
  __syncthreads();
  if (tid < 128) {
    int cls = tid >> 6, bb = tid & 63;
    float s = 0.f;
#pragma unroll
    for (int q = 0; q < 8; q++) s += gl[cls * 8 + q][bb];
    part[(size_t)blockIdx.x * 128 + cls * 64 + bb] = s;
  }
  gridbar(bar, target);
  if (blockIdx.x == 0 && tid < 128) {
    int cls = tid >> 6, bb = tid & 63;
    float s = bcls[cls];
    for (int k = 0; k < NBLK; k++) s += part[(size_t)k * 128 + cls * 64 + bb];
    out[bb * 2 + cls] = s;
  }
}

extern "C" void kernel_launch(void* const* d_in, const int* in_sizes, int n_in,
                              void* d_out, int out_size, void* d_ws, size_t ws_size,
                              hipStream_t stream) {
  const int*   x    = (const int*)d_in[0];
  const int*   len  = (const int*)d_in[1];
  const float* emb  = (const float*)d_in[2];
  const float* Wih  = (const float*)d_in[3];
  const float* Whh  = (const float*)d_in[4];
  const float* bih  = (const float*)d_in[5];
  const float* bhh  = (const float*)d_in[6];
  const float* Wcls = (const float*)d_in[7];
  const float* bcls = (const float*)d_in[8];
  float* out = (float*)d_out;

  char* ws = (char*)d_ws;
  short* weB  = (short*)ws;                                   // 16,777,216 B
  short* Wall = (short*)(ws + (size_t)16777216);              //  5,242,880 B
  short* hbuf = (short*)(ws + (size_t)16777216 + 5242880);    //    131,072 B
  float* part = (float*)(ws + (size_t)16777216 + 5242880 + 131072);  // 32,768 B
  int*   bar  = (int*)(ws + (size_t)16777216 + 5242880 + 131072 + 32768);

  zero_kernel<<<dim3(64), dim3(256), 0, stream>>>((unsigned*)hbuf, bar);
  gather_kernel<<<dim3(TN), dim3(256), 0, stream>>>(weB, x, emb);
  prep_w_kernel<<<dim3((2048 * KCAT) / 256), dim3(256), 0, stream>>>(Wall, Wih, Whh);

  void* args[] = { (void*)&weB, (void*)&Wall, (void*)&hbuf, (void*)&len,
                   (void*)&bih, (void*)&bhh, (void*)&Wcls, (void*)&bcls,
                   (void*)&part, (void*)&bar, (void*)&out };
  hipLaunchCooperativeKernel((void*)scan_kernel, dim3(NBLK), dim3(512),
                             args, 0, stream);
}

// Round 3
// 5880.687 us; speedup vs baseline: 3.6269x; 1.9925x over previous
//
#include <hip/hip_runtime.h>
#include <hip/hip_bf16.h>

#define EN 256
#define HN 512
#define BN 64
#define TN 512
#define NBLK 64
#define KCAT 1280   // 256 Wih_hi | 512 Whh_hi | 512 Whh_lo

typedef __attribute__((ext_vector_type(8))) short short8;
typedef __attribute__((ext_vector_type(4))) short short4v;
typedef __attribute__((ext_vector_type(4))) float f32x4;

union QW { unsigned long long q[2]; short8 v; };

#define SCOPE __HIP_MEMORY_SCOPE_AGENT

__device__ inline short bf_of(float f) {
  __hip_bfloat16 h = __float2bfloat16(f);
  return *reinterpret_cast<short*>(&h);
}
__device__ inline float f_of_bf(short s) {
  __hip_bfloat16 h = *reinterpret_cast<__hip_bfloat16*>(&s);
  return __bfloat162float(h);
}

// ---------- K0: zero h-buffer 0, arrival slots, release word (LLC-visible) --
__global__ __launch_bounds__(256) void zero_kernel(
    unsigned long long* hbuf64, unsigned* arr, unsigned* rel) {
  int idx = blockIdx.x * 256 + threadIdx.x;
  if (idx < BN * HN / 4)
    __hip_atomic_store(&hbuf64[idx], 0ULL, __ATOMIC_RELAXED, SCOPE);
  if (idx < NBLK * 32)
    __hip_atomic_store(&arr[idx], 0u, __ATOMIC_RELAXED, SCOPE);
  if (idx == 0)
    __hip_atomic_store(rel, 0u, __ATOMIC_RELAXED, SCOPE);
}

// ---------- K1: weB[t*64+b][k] = bf16(emb[x[b][t]][k]) ----------
__global__ __launch_bounds__(256) void gather_kernel(
    short* __restrict__ weB, const int* __restrict__ x,
    const float* __restrict__ emb) {
  const int t = blockIdx.x;
  const int tid = threadIdx.x;
  const int b = tid >> 2, q = tid & 3;
  const int row = x[b * TN + t];
  const float4* src = (const float4*)(emb + (size_t)row * EN + q * 64);
  short* dst = weB + ((size_t)(t * 64 + b)) * EN + q * 64;
#pragma unroll
  for (int i = 0; i < 16; i++) {
    float4 v = src[i];
    short4v o = { bf_of(v.x), bf_of(v.y), bf_of(v.z), bf_of(v.w) };
    *(short4v*)(dst + i * 4) = o;
  }
}

// ---------- K2: Wall[grow][kc]: kc<256 Wih_hi | <768 Whh_hi | else Whh_lo --
__global__ __launch_bounds__(256) void prep_w_kernel(
    short* __restrict__ Wall, const float* __restrict__ Wih,
    const float* __restrict__ Whh) {
  int idx = blockIdx.x * 256 + threadIdx.x;   // 2048*1280 total
  int grow = idx / KCAT, kc = idx - grow * KCAT;
  float v;
  if (kc < 256) {
    v = Wih[(size_t)grow * EN + kc];
  } else if (kc < 768) {
    v = Whh[(size_t)grow * HN + (kc - 256)];
  } else {
    float f = Whh[(size_t)grow * HN + (kc - 768)];
    v = f - f_of_bf(bf_of(f));                // residual (lo) term
  }
  Wall[idx] = bf_of(v);
}

// ---------- distributed grid barrier: no RMW contention, no acquire spins --
__device__ __forceinline__ void gridbar(unsigned* arr, unsigned* rel,
                                        unsigned want, int bid, int tid) {
  __syncthreads();   // drains each wave's vmcnt -> h stores acked at LLC
  if (tid == 0)
    __hip_atomic_store(&arr[bid * 32], want, __ATOMIC_RELEASE, SCOPE);
  if (bid == 0) {
    if (tid < NBLK) {
      while (__hip_atomic_load(&arr[tid * 32], __ATOMIC_RELAXED, SCOPE) < want)
        __builtin_amdgcn_s_sleep(1);
    }
    __syncthreads();
    if (tid == 0)
      __hip_atomic_store(rel, want, __ATOMIC_RELAXED, SCOPE);
  } else {
    if (tid == 0) {
      while (__hip_atomic_load(rel, __ATOMIC_RELAXED, SCOPE) < want)
        __builtin_amdgcn_s_sleep(1);
    }
    __syncthreads();
  }
}

// ---------- scan: 64 blocks x 512 thr, block owns h-cols [8*blk, 8*blk+8) --
__global__ __launch_bounds__(512, 2) void scan_kernel(
    const short* __restrict__ weB, const short* __restrict__ Wall,
    unsigned long long* __restrict__ hbuf64, const int* __restrict__ length,
    const float* __restrict__ bih, const float* __restrict__ bhh,
    const float* __restrict__ Wcls, const float* __restrict__ bcls,
    float* __restrict__ part, unsigned* arr, unsigned* rel,
    float* __restrict__ out) {
  __shared__ float gl[32][64];            // gate rows r = type*8+jj, col b
  __shared__ __align__(8) short hstage[BN][8];
  const int tid = threadIdx.x;
  const int l = tid & 63, w = tid >> 6;
  const int bid = blockIdx.x;
  const int j0 = bid * 8;

  // --- MFMA role: wave w -> C rows [rhalf,+16), cols [btile,+16)
  const int btile = (w & 3) * 16;
  const int rhalf = (w >> 2) * 16;

  short8 aH[24], aL[16];
  {
    int r = rhalf + (l & 15);
    int grow = (r >> 3) * HN + j0 + (r & 7);
    const short* wp = Wall + (size_t)grow * KCAT + 8 * (l >> 4);
#pragma unroll
    for (int kk = 0; kk < 24; kk++) aH[kk] = *(const short8*)(wp + kk * 32);
#pragma unroll
    for (int kk = 0; kk < 16; kk++) aL[kk] = *(const short8*)(wp + 768 + kk * 32);
  }

  // --- elementwise role: thread -> (jj = w, b = l)
  const int jj = w, b = l;
  float bias[4];
#pragma unroll
  for (int ty = 0; ty < 4; ty++) {
    int grow = ty * HN + j0 + jj;
    bias[ty] = bih[grow] + bhh[grow];
  }
  const int len = length[b];
  float c = 0.f, fmx = -INFINITY;

  const int HROW64 = HN / 4;              // u64 per h row
  for (int t = 0; t < TN; t++) {
    const unsigned long long* hrow = hbuf64
        + (size_t)(t & 1) * (BN * HROW64)
        + (size_t)(btile + (l & 15)) * HROW64 + 2 * (l >> 4);
    const short* xrow = weB + ((size_t)(t * 64 + btile + (l & 15))) * EN + 8 * (l >> 4);

    f32x4 accH = {0.f, 0.f, 0.f, 0.f}, accL = {0.f, 0.f, 0.f, 0.f};
    QW hf[8];
    // preload h fragments 0..7 (LLC bypass), overlap with x-side chain
#pragma unroll
    for (int kk = 0; kk < 8; kk++) {
      hf[kk].q[0] = __hip_atomic_load(hrow + (size_t)kk * 8,     __ATOMIC_RELAXED, SCOPE);
      hf[kk].q[1] = __hip_atomic_load(hrow + (size_t)kk * 8 + 1, __ATOMIC_RELAXED, SCOPE);
    }
#pragma unroll
    for (int kk = 0; kk < 8; kk++) {      // x-side: K = 0..255 (L2-cached)
      short8 bf = *(const short8*)(xrow + kk * 32);
      accH = __builtin_amdgcn_mfma_f32_16x16x32_bf16(aH[kk], bf, accH, 0, 0, 0);
    }
#pragma unroll
    for (int half = 0; half < 2; half++) {
      if (half == 1) {
#pragma unroll
        for (int kk = 0; kk < 8; kk++) {
          hf[kk].q[0] = __hip_atomic_load(hrow + (size_t)(8 + kk) * 8,     __ATOMIC_RELAXED, SCOPE);
          hf[kk].q[1] = __hip_atomic_load(hrow + (size_t)(8 + kk) * 8 + 1, __ATOMIC_RELAXED, SCOPE);
        }
      }
#pragma unroll
      for (int kk = 0; kk < 8; kk++) {    // h-side hi+lo chains
        int ki = half * 8 + kk;
        accH = __builtin_amdgcn_mfma_f32_16x16x32_bf16(aH[8 + ki], hf[kk].v, accH, 0, 0, 0);
        accL = __builtin_amdgcn_mfma_f32_16x16x32_bf16(aL[ki],     hf[kk].v, accL, 0, 0, 0);
      }
    }
#pragma unroll
    for (int q = 0; q < 4; q++) {         // C/D: col = lane&15, row = (lane>>4)*4+q
      int r = rhalf + (l >> 4) * 4 + q;
      gl[r][btile + (l & 15)] = accH[q] + accL[q];
    }
    __syncthreads();
    {
      float gi = gl[0 + jj][b] + bias[0];
      float gf = gl[8 + jj][b] + bias[1];
      float gg = gl[16 + jj][b] + bias[2];
      float go = gl[24 + jj][b] + bias[3];
      float si = 1.f / (1.f + __expf(-gi));
      float sf = 1.f / (1.f + __expf(-gf));
      float so = 1.f / (1.f + __expf(-go));
      float tg = 2.f / (1.f + __expf(-2.f * gg)) - 1.f;
      c = sf * c + si * tg;
      float tc = 2.f / (1.f + __expf(-2.f * c)) - 1.f;
      float h = so * tc;
      hstage[b][jj] = bf_of(h);
      if (t < len) fmx = fmaxf(fmx, h);
    }
    __syncthreads();
    if (tid < 128) {                      // pack 4 bf16 -> one u64 LLC store
      int bb = tid >> 1, half = tid & 1;
      unsigned long long pk = *(const unsigned long long*)&hstage[bb][half * 4];
      __hip_atomic_store(hbuf64 + (size_t)((t + 1) & 1) * (BN * HROW64)
                             + (size_t)bb * HROW64 + bid * 2 + half,
                         pk, __ATOMIC_RELAXED, SCOPE);
    }
    gridbar(arr, rel, (unsigned)(t + 1), bid, tid);
  }

  // --- classifier partials ---
  gl[jj][b]     = fmx * Wcls[j0 + jj];
  gl[8 + jj][b] = fmx * Wcls[HN + j0 + jj];
  __syncthreads();
  if (tid < 128) {
    int cls = tid >> 6, bb = tid & 63;
    float s = 0.f;
#pragma unroll
    for (int q = 0; q < 8; q++) s += gl[cls * 8 + q][bb];
    __hip_atomic_store(&part[(size_t)bid * 128 + cls * 64 + bb], s,
                       __ATOMIC_RELAXED, SCOPE);
  }
  gridbar(arr, rel, (unsigned)(TN + 1), bid, tid);
  if (bid == 0 && tid < 128) {
    int cls = tid >> 6, bb = tid & 63;
    float s = bcls[cls];
    for (int k = 0; k < NBLK; k++)
      s += __hip_atomic_load(&part[(size_t)k * 128 + cls * 64 + bb],
                             __ATOMIC_RELAXED, SCOPE);
    out[bb * 2 + cls] = s;
  }
}

extern "C" void kernel_launch(void* const* d_in, const int* in_sizes, int n_in,
                              void* d_out, int out_size, void* d_ws, size_t ws_size,
                              hipStream_t stream) {
  const int*   x    = (const int*)d_in[0];
  const int*   len  = (const int*)d_in[1];
  const float* emb  = (const float*)d_in[2];
  const float* Wih  = (const float*)d_in[3];
  const float* Whh  = (const float*)d_in[4];
  const float* bih  = (const float*)d_in[5];
  const float* bhh  = (const float*)d_in[6];
  const float* Wcls = (const float*)d_in[7];
  const float* bcls = (const float*)d_in[8];
  float* out = (float*)d_out;

  char* ws = (char*)d_ws;
  short* weB  = (short*)ws;                                   // 16,777,216 B
  short* Wall = (short*)(ws + 16777216ull);                   //  5,242,880 B
  unsigned long long* hbuf64 =
      (unsigned long long*)(ws + 16777216ull + 5242880);      //    131,072 B
  float* part = (float*)(ws + 16777216ull + 5242880 + 131072);          // 32 KB
  unsigned* arrp = (unsigned*)(ws + 16777216ull + 5242880 + 131072 + 32768); // 8 KB
  unsigned* relp = (unsigned*)(ws + 16777216ull + 5242880 + 131072 + 32768 + 8192);

  zero_kernel<<<dim3(32), dim3(256), 0, stream>>>(hbuf64, arrp, relp);
  gather_kernel<<<dim3(TN), dim3(256), 0, stream>>>(weB, x, emb);
  prep_w_kernel<<<dim3((2048 * KCAT) / 256), dim3(256), 0, stream>>>(Wall, Wih, Whh);

  void* args[] = { (void*)&weB, (void*)&Wall, (void*)&hbuf64, (void*)&len,
                   (void*)&bih, (void*)&bhh, (void*)&Wcls, (void*)&bcls,
                   (void*)&part, (void*)&arrp, (void*)&relp, (void*)&out };
  hipLaunchCooperativeKernel((void*)scan_kernel, dim3(NBLK), dim3(512),
                             args, 0, stream);
}